// Round 2
// baseline (5030.157 us; speedup 1.0000x reference)
//
#include <hip/hip_runtime.h>
#include <math.h>

#define NCLS 19
#define KM 190
#define KMP 192
#define D 720
#define TP 128
#define KC 36
#define NCH 20
#define LDX 44
#define XSLOT 11

__device__ __forceinline__ float wred_sum(float v) {
#pragma unroll
  for (int o = 32; o > 0; o >>= 1) v += __shfl_xor(v, o, 64);
  return v;
}
__device__ __forceinline__ float wred_max(float v) {
#pragma unroll
  for (int o = 32; o > 0; o >>= 1) v = fmaxf(v, __shfl_xor(v, o, 64));
  return v;
}
__device__ __forceinline__ double wred_sumd(double v) {
#pragma unroll
  for (int o = 32; o > 0; o >>= 1) v += __shfl_xor(v, o, 64);
  return v;
}

#define GLD16(src, dst)                                                        \
  __builtin_amdgcn_global_load_lds(                                            \
      (const __attribute__((address_space(1))) void*)(src),                    \
      (__attribute__((address_space(3))) void*)(dst), 16, 0, 0)
#define GLD4(src, dst)                                                         \
  __builtin_amdgcn_global_load_lds(                                            \
      (const __attribute__((address_space(1))) void*)(src),                    \
      (__attribute__((address_space(3))) void*)(dst), 4, 0, 0)

// ---------------- fused prep: pgT (+stat cols), Av/Bv, G2, C3, zero f/cnt
__global__ void prep_all(const float* __restrict__ pr, const float* __restrict__ fg,
                         const float* __restrict__ fb, float* __restrict__ pgT,
                         float* __restrict__ Av, float* __restrict__ Bv,
                         float* __restrict__ G2, float* __restrict__ C3,
                         float* __restrict__ f, int* __restrict__ cnt) {
  const int j = blockIdx.x, lane = threadIdx.x;
  if (j == 192) {
    float cg = 0.f, cgb = 0.f, cb = 0.f;
    for (int d = lane; d < D; d += 64) {
      const float g = fg[d], b = fb[d];
      G2[d] = g * g;
      cg = fmaf(g, g, cg);
      cgb = fmaf(g, b, cgb);
      cb = fmaf(b, b, cb);
    }
    cg = wred_sum(cg);
    cgb = wred_sum(cgb);
    cb = wred_sum(cb);
    if (lane == 0) { C3[0] = cg; C3[1] = cgb; C3[2] = cb; cnt[0] = 0; }
    return;
  }
  if (j < KM) {
    for (int d = lane; d < D; d += 64) f[(size_t)j * D + d] = 0.f;
  }
  if (j >= KM) {
    // stat columns: col 190 -> g^2 (gives Sum x g^2), col 191 -> g*b (Sum x g b)
    for (int d = lane; d < D; d += 64) {
      const float g = fg[d], b = fb[d];
      pgT[(size_t)d * KMP + j] = (j == KM) ? g * g : g * b;
    }
    if (lane == 0) { Av[j] = 0.f; Bv[j] = 0.f; }
    return;
  }
  float pv[12];
  float sp = 0.f;
#pragma unroll
  for (int jj = 0; jj < 12; ++jj) {
    const int d2 = lane + 64 * jj;
    pv[jj] = (d2 < D) ? pr[(size_t)j * D + d2] : 0.f;
    sp = fmaf(pv[jj], pv[jj], sp);
  }
  sp = wred_sum(sp);
  const float ip = 1.f / fmaxf(sqrtf(sp), 1e-12f);
  float sa = 0.f, sb = 0.f;
#pragma unroll
  for (int jj = 0; jj < 12; ++jj) {
    const int d2 = lane + 64 * jj;
    if (d2 < D) {
      const float ph = pv[jj] * ip;
      const float g = fg[d2], b = fb[d2];
      pgT[(size_t)d2 * KMP + j] = g * ph;
      sa = fmaf(g, ph, sa);
      sb = fmaf(b, ph, sb);
    }
  }
  sa = wred_sum(sa);
  sb = wred_sum(sb);
  if (lane == 0) { Av[j] = sa; Bv[j] = sb; }
}

// ---------------- main pass: DMA-staged GEMM on raw x + affine fixup + epilogue
__global__ __launch_bounds__(256, 3) void gemm_main(
    const float* __restrict__ x, const float* __restrict__ pgT,
    const float* __restrict__ Av, const float* __restrict__ Bv,
    const float* __restrict__ G2, const float* __restrict__ C3,
    const int* __restrict__ gt, float* __restrict__ out_seg,
    float* __restrict__ contrast, float* __restrict__ se,
    int* __restrict__ flags, const float* __restrict__ mn_g,
    const float* __restrict__ mn_b, const float* __restrict__ pn_g,
    const float* __restrict__ pn_b) {
  __shared__ union {
    struct {
      float PT[KC][KMP];   // 27648 B, contiguous for DMA
      float XL[TP][LDX];   // 22528 B row-major, ldx=44 (slot 9/10 pad)
      float G2c[64];       // 256 B (36 used)
    } st;
    float SIM[64][KMP];    // 49152 B (reused per half)
  } S;
  __shared__ float MU[TP], RS[TP], IL[TP];
  __shared__ float S1v[TP], S3v[TP];

  const int t = threadIdx.x;
  const int n0 = blockIdx.x * TP;
  const int pxg = t & 15;        // pixel group: px = pxg + 16*i, i=0..7
  const int prg = t >> 4;        // proto group: j = 12*prg + jj
  const int lane = t & 63, w = t >> 6;
  const int spx = 32 * w + (lane >> 1);  // stats pixel for this lane-pair
  const int sh = lane & 1;               // k-half (cols 0..17 / 18..35)

  const float Cgg = C3[0], Cgb = C3[1], Cbb = C3[2];

  float acc[8][12];
#pragma unroll
  for (int i = 0; i < 8; ++i)
#pragma unroll
    for (int jj = 0; jj < 12; ++jj) acc[i][jj] = 0.f;
  float s0 = 0.f, qs = 0.f, s2 = 0.f;

#pragma unroll 1
  for (int c = 0; c < NCH; ++c) {
    const int k0 = c * KC;
    __syncthreads();
    // --- async DMA staging (wave-uniform LDS base + lane*16 scatter) ---
    {
      const float* psrc = pgT + (size_t)k0 * KMP + (lane << 2);
      char* pdst = (char*)&S.st.PT[0][0];
      for (int i = w; i < 27; i += 4) GLD16(psrc + (i << 8), pdst + (i << 10));
      char* xdst = (char*)&S.st.XL[0][0];
      for (int i = w; i < 22; i += 4) {
        const int s = (i << 6) + lane;      // flat float4 slot, row-major ldx
        const int row = s / 11;
        int cc = s - row * 11;
        cc = cc > 8 ? 8 : cc;               // clamp pad slots (never read)
        GLD16(x + (size_t)(n0 + row) * D + k0 + (cc << 2), xdst + (i << 10));
      }
      if (w == 0) {
        const int gl = lane > 35 ? 35 : lane;
        GLD4(G2 + k0 + gl, (char*)&S.st.G2c[0]);
      }
    }
    __syncthreads();
    // --- register-tile FMA: 8 px x 12 protos, k vectorized by 4 ---
    const float4* XL4 = (const float4*)&S.st.XL[0][0];
    const float4* PT4 = (const float4*)&S.st.PT[0][0];
#pragma unroll 1
    for (int kc = 0; kc < 9; ++kc) {
      float4 xv[8];
#pragma unroll
      for (int i = 0; i < 8; ++i) xv[i] = XL4[(pxg + (i << 4)) * XSLOT + kc];
#pragma unroll
      for (int r = 0; r < 4; ++r) {
        const int kk = (kc << 2) + r;
        const float4 p0 = PT4[kk * 48 + 3 * prg + 0];
        const float4 p1 = PT4[kk * 48 + 3 * prg + 1];
        const float4 p2 = PT4[kk * 48 + 3 * prg + 2];
        const float pj[12] = {p0.x, p0.y, p0.z, p0.w, p1.x, p1.y,
                              p1.z, p1.w, p2.x, p2.y, p2.z, p2.w};
#pragma unroll
        for (int i = 0; i < 8; ++i) {
          const float xr = r == 0 ? xv[i].x : r == 1 ? xv[i].y
                         : r == 2 ? xv[i].z : xv[i].w;
#pragma unroll
          for (int jj = 0; jj < 12; ++jj)
            acc[i][jj] = fmaf(xr, pj[jj], acc[i][jj]);
        }
      }
    }
    // --- per-pixel stats (lane-pair splits k-halves): s0, q, Sum x^2 g^2 ---
    {
      const float2* xr2 = (const float2*)&S.st.XL[spx][18 * sh];
      const float2* gr2 = (const float2*)&S.st.G2c[18 * sh];
#pragma unroll
      for (int mm = 0; mm < 9; ++mm) {
        const float2 xv2 = xr2[mm];
        const float2 gv2 = gr2[mm];
        s0 += xv2.x + xv2.y;
        qs = fmaf(xv2.x, xv2.x, qs);
        qs = fmaf(xv2.y, xv2.y, qs);
        s2 = fmaf(xv2.x * xv2.x, gv2.x, s2);
        s2 = fmaf(xv2.y * xv2.y, gv2.y, s2);
      }
    }
  }

  // linear stats came out of the GEMM (cols 190, 191)
  if (prg == 15) {
#pragma unroll
    for (int i = 0; i < 8; ++i) {
      S1v[pxg + (i << 4)] = acc[i][10];
      S3v[pxg + (i << 4)] = acc[i][11];
    }
  }
  __syncthreads();
  s0 += __shfl_xor(s0, 1);
  qs += __shfl_xor(qs, 1);
  s2 += __shfl_xor(s2, 1);
  if (sh == 0) {
    const float muv = s0 / 720.f;
    const float var = qs / 720.f - muv * muv;
    const float rsv = 1.f / sqrtf(var + 1e-5f);
    const float s1v = S1v[spx], s3v = S3v[spx];
    const float L2v = rsv * rsv * (s2 - 2.f * muv * s1v + muv * muv * Cgg) +
                      2.f * rsv * (s3v - muv * Cgb) + Cbb;
    MU[spx] = muv;
    RS[spx] = rsv;
    IL[spx] = 1.f / fmaxf(sqrtf(fmaxf(L2v, 0.f)), 1e-12f);
  }

  float Aj[12], Bj[12];
#pragma unroll
  for (int jj = 0; jj < 12; ++jj) {
    Aj[jj] = Av[12 * prg + jj];
    Bj[jj] = Bv[12 * prg + jj];
  }
  const int j0 = lane, j1 = lane + 64, j2 = lane + 128;
  const bool ok2 = j2 < KM;
  const float pg0 = pn_g[j0], pb0 = pn_b[j0];
  const float pg1 = pn_g[j1], pb1 = pn_b[j1];
  const float pg2 = ok2 ? pn_g[j2] : 0.f, pb2 = ok2 ? pn_b[j2] : 0.f;
  const float mgv = lane < NCLS ? mn_g[lane] : 0.f;
  const float mbv = lane < NCLS ? mn_b[lane] : 0.f;

#pragma unroll
  for (int h = 0; h < 2; ++h) {
    __syncthreads();
    // fixup to cosine sims + SIM write for this half's 64 pixels
#pragma unroll
    for (int i2 = 0; i2 < 4; ++i2) {
      const int i = 4 * h + i2;
      const int px = pxg + (i << 4);
      const float muv = MU[px], rsv = RS[px], ilv = IL[px];
      float v[12];
#pragma unroll
      for (int jj = 0; jj < 12; ++jj)
        v[jj] = (rsv * (acc[i][jj] - muv * Aj[jj]) + Bj[jj]) * ilv;
      float4* dst = (float4*)&S.SIM[px - 64 * h][12 * prg];
      dst[0] = make_float4(v[0], v[1], v[2], v[3]);
      dst[1] = make_float4(v[4], v[5], v[6], v[7]);
      dst[2] = make_float4(v[8], v[9], v[10], v[11]);
    }
    __syncthreads();
    // epilogue: wave w handles local rows 16w..16w+15
    for (int pi = 0; pi < 16; ++pi) {
      const int pix = 16 * w + pi;
      const int n = n0 + 64 * h + pix;
      const float sv0 = S.SIM[pix][j0];
      const float sv1 = S.SIM[pix][j1];
      const float sv2 = ok2 ? S.SIM[pix][j2] : 0.f;
      float sum = wred_sum(sv0 + sv1 + sv2);
      const float mu = sum / 190.f;
      const float d0 = sv0 - mu, d1 = sv1 - mu, d2v = ok2 ? (sv2 - mu) : 0.f;
      float vs = wred_sum(d0 * d0 + d1 * d1 + d2v * d2v);
      const float rstd = 1.f / sqrtf(vs / 190.f + 1e-5f);
      contrast[(size_t)n * KM + j0] = d0 * rstd * pg0 + pb0;
      contrast[(size_t)n * KM + j1] = d1 * rstd * pg1 + pb1;
      if (ok2) contrast[(size_t)n * KM + j2] = d2v * rstd * pg2 + pb2;
      const int g0 = gt[n];
      const int b10 = g0 * 10;
      if (j0 >= b10 && j0 < b10 + 10) se[(size_t)n * 10 + (j0 - b10)] = sv0;
      if (j1 >= b10 && j1 < b10 + 10) se[(size_t)n * 10 + (j1 - b10)] = sv1;
      if (ok2 && j2 >= b10 && j2 < b10 + 10) se[(size_t)n * 10 + (j2 - b10)] = sv2;
      float mx = -3.0e38f;
      if (lane < NCLS) {
        const float* row = &S.SIM[pix][lane * 10];
#pragma unroll
        for (int m2 = 0; m2 < 10; ++m2) mx = fmaxf(mx, row[m2]);
      }
      float s19 = wred_sum(lane < NCLS ? mx : 0.f);
      const float mu19 = s19 / 19.f;
      const float dv = (lane < NCLS) ? (mx - mu19) : 0.f;
      float v19 = wred_sum(dv * dv);
      const float rs19 = 1.f / sqrtf(v19 / 19.f + 1e-5f);
      float key = -3.0e38f;
      if (lane < NCLS) {
        const float os = dv * rs19 * mgv + mbv;
        out_seg[(size_t)n * NCLS + lane] = os;
        key = os;
      }
      const float kmax = wred_max(key);
      const unsigned long long bm = __ballot(key == kmax);
      const int pred = __ffsll((unsigned long long)bm) - 1;
      if (lane == 0) flags[n] = (pred == g0) ? 1 : 0;
    }
  }
}

// ---------------- fused Sinkhorn: one block per class, no grid sync needed
__global__ void sk_all(const float* __restrict__ se, const int* __restrict__ gt,
                       const int* __restrict__ flags, float* __restrict__ ptgt,
                       int* __restrict__ list, int* __restrict__ cnt,
                       int* __restrict__ n_km, int N) {
  const int k = blockIdx.x, t = threadIdx.x;
  const int lane = t & 63, w = t >> 6;
  __shared__ float u_s[10];
  __shared__ double redm[4][10];
  __shared__ int nkm_l[10];
  for (int iter = 0; iter < 3; ++iter) {
    double acc[10];
#pragma unroll
    for (int m = 0; m < 10; ++m) acc[m] = 0.0;
    for (int n = t; n < N; n += 256) {
      if (gt[n] != k) continue;
      float e[10];
#pragma unroll
      for (int m = 0; m < 10; ++m) e[m] = expf(se[(size_t)n * 10 + m] / 0.05f);
      float a = 1.f;
      if (iter > 0) {
        float s = 0.f;
#pragma unroll
        for (int m = 0; m < 10; ++m) s = fmaf(e[m], u_s[m], s);
        a = s > 0.f ? 1.f / s : 0.f;
      }
#pragma unroll
      for (int m = 0; m < 10; ++m) acc[m] += (double)(a * e[m]);
    }
#pragma unroll
    for (int m = 0; m < 10; ++m) {
      double v = wred_sumd(acc[m]);
      if (lane == 0) redm[w][m] = v;
    }
    __syncthreads();
    if (t < 10) {
      const double sv = redm[0][t] + redm[1][t] + redm[2][t] + redm[3][t];
      u_s[t] = sv > 0.0 ? (float)(1.0 / (10.0 * sv)) : 0.f;
    }
    __syncthreads();
  }
  if (t < 10) nkm_l[t] = 0;
  __syncthreads();
  for (int n = t; n < N; n += 256) {
    if (gt[n] != k) continue;
    float best = -1.f;
    int bi = 0;
#pragma unroll
    for (int m = 0; m < 10; ++m) {
      const float v = expf(se[(size_t)n * 10 + m] / 0.05f) * u_s[m];
      if (v > best) { best = v; bi = m; }
    }
    ptgt[n] = (float)(bi + 10 * k);
    if (flags[n]) {
      atomicAdd(&nkm_l[bi], 1);
      const int p = atomicAdd(cnt, 1);
      list[p] = n | (bi << 20) | (k << 24);
    }
  }
  __syncthreads();
  if (t < 10) n_km[10 * k + t] = nkm_l[t];
}

// ---------------- f accumulation over correct pixels (wave per pixel)
__global__ void f_accum(const float* __restrict__ x, const float* __restrict__ fg,
                        const float* __restrict__ fb, const int* __restrict__ list,
                        const int* __restrict__ cnt, float* __restrict__ f) {
  const int lane = threadIdx.x & 63;
  const int wid = (blockIdx.x * blockDim.x + threadIdx.x) >> 6;
  const int nw = (gridDim.x * blockDim.x) >> 6;
  const int total = *cnt;
  for (int i = wid; i < total; i += nw) {
    const int packed = list[i];
    const int n = packed & 0xFFFFF;
    const int m = (packed >> 20) & 0xF;
    const int k = (packed >> 24) & 0x1F;
    float xv[12];
    float s0 = 0.f, q = 0.f;
#pragma unroll
    for (int jj = 0; jj < 12; ++jj) {
      const int d2 = lane + 64 * jj;
      xv[jj] = (d2 < D) ? x[(size_t)n * D + d2] : 0.f;
      s0 += xv[jj];
      q = fmaf(xv[jj], xv[jj], q);
    }
    s0 = wred_sum(s0);
    q = wred_sum(q);
    const float mu = s0 / 720.f;
    const float var = q / 720.f - mu * mu;
    const float rs = 1.f / sqrtf(var + 1e-5f);
    float cv[12];
    float l2 = 0.f;
#pragma unroll
    for (int jj = 0; jj < 12; ++jj) {
      const int d2 = lane + 64 * jj;
      if (d2 < D) {
        cv[jj] = (xv[jj] - mu) * rs * fg[d2] + fb[d2];
        l2 = fmaf(cv[jj], cv[jj], l2);
      } else {
        cv[jj] = 0.f;
      }
    }
    l2 = wred_sum(l2);
    const float il = 1.f / fmaxf(sqrtf(l2), 1e-12f);
    float* frow = &f[(size_t)(k * 10 + m) * D];
#pragma unroll
    for (int jj = 0; jj < 12; ++jj) {
      const int d2 = lane + 64 * jj;
      if (d2 < D) atomicAdd(&frow[d2], cv[jj] * il);
    }
  }
}

// ---------------- prototype update (one wave per proto row)
__global__ void protos_out(const float* __restrict__ pr, const float* __restrict__ f,
                           const int* __restrict__ n_km, float* __restrict__ out) {
  const int j = blockIdx.x, lane = threadIdx.x;
  float pv[12], fv[12];
  float sp = 0.f, sf = 0.f;
#pragma unroll
  for (int jj = 0; jj < 12; ++jj) {
    const int d2 = lane + 64 * jj;
    pv[jj] = (d2 < D) ? pr[(size_t)j * D + d2] : 0.f;
    fv[jj] = (d2 < D) ? f[(size_t)j * D + d2] : 0.f;
    sp = fmaf(pv[jj], pv[jj], sp);
    sf = fmaf(fv[jj], fv[jj], sf);
  }
  sp = wred_sum(sp);
  sf = wred_sum(sf);
  const float ip = 1.f / fmaxf(sqrtf(sp), 1e-12f);
  const float iff = 1.f / fmaxf(sqrtf(sf), 1e-12f);
  const bool valid = n_km[j] > 0;
  float vv[12];
  float sv = 0.f;
#pragma unroll
  for (int jj = 0; jj < 12; ++jj) {
    const float ph = pv[jj] * ip;
    vv[jj] = valid ? (0.999f * ph + 0.001f * (fv[jj] * iff)) : ph;
    sv = fmaf(vv[jj], vv[jj], sv);
  }
  sv = wred_sum(sv);
  const float ivv = 1.f / fmaxf(sqrtf(sv), 1e-12f);
#pragma unroll
  for (int jj = 0; jj < 12; ++jj) {
    const int d2 = lane + 64 * jj;
    if (d2 < D) out[(size_t)j * D + d2] = vv[jj] * ivv;
  }
}

extern "C" void kernel_launch(void* const* d_in, const int* in_sizes, int n_in,
                              void* d_out, int out_size, void* d_ws, size_t ws_size,
                              hipStream_t stream) {
  const float* x = (const float*)d_in[0];
  const float* protos = (const float*)d_in[1];
  const float* fn_g = (const float*)d_in[2];
  const float* fn_b = (const float*)d_in[3];
  const float* mn_g = (const float*)d_in[4];
  const float* mn_b = (const float*)d_in[5];
  const float* pn_g = (const float*)d_in[6];
  const float* pn_b = (const float*)d_in[7];
  const int* gt = (const int*)d_in[8];
  const int N = in_sizes[0] / D;

  float* out_seg = (float*)d_out;
  float* contrast = out_seg + (size_t)N * NCLS;
  float* ptgt = contrast + (size_t)N * KM;
  float* pnew = ptgt + (size_t)N;

  char* ws = (char*)d_ws;
  size_t off = 0;
  auto alloc = [&](size_t bytes) {
    char* p = ws + off;
    off = (off + bytes + 255) & ~(size_t)255;
    return p;
  };
  float* pgT = (float*)alloc((size_t)D * KMP * 4 + 1024);
  float* Av = (float*)alloc(KMP * 4);
  float* Bv = (float*)alloc(KMP * 4);
  float* G2 = (float*)alloc(D * 4);
  float* C3 = (float*)alloc(4 * 4);
  float* se = (float*)alloc((size_t)N * 10 * 4);
  float* f = (float*)alloc((size_t)KM * D * 4);
  int* n_km = (int*)alloc(KMP * 4);
  int* flags = (int*)alloc((size_t)N * 4);
  int* list = (int*)alloc((size_t)N * 4);
  int* cnt = (int*)alloc(256);

  prep_all<<<193, 64, 0, stream>>>(protos, fn_g, fn_b, pgT, Av, Bv, G2, C3, f, cnt);
  gemm_main<<<N / TP, 256, 0, stream>>>(x, pgT, Av, Bv, G2, C3, gt, out_seg,
                                        contrast, se, flags, mn_g, mn_b, pn_g,
                                        pn_b);
  sk_all<<<NCLS, 256, 0, stream>>>(se, gt, flags, ptgt, list, cnt, n_km, N);
  f_accum<<<256, 256, 0, stream>>>(x, fn_g, fn_b, list, cnt, f);
  protos_out<<<KM, 64, 0, stream>>>(protos, f, n_km, pnew);
}

// Round 3
// 1721.626 us; speedup vs baseline: 2.9217x; 2.9217x over previous
//
#include <hip/hip_runtime.h>
#include <math.h>

#define NCLS 19
#define KM 190
#define KMP 192
#define D 720
#define TP 128
#define KC 36
#define NCH 20
#define LDX 44
#define XSLOT 11

__device__ __forceinline__ float wred_sum(float v) {
#pragma unroll
  for (int o = 32; o > 0; o >>= 1) v += __shfl_xor(v, o, 64);
  return v;
}
__device__ __forceinline__ float wred_max(float v) {
#pragma unroll
  for (int o = 32; o > 0; o >>= 1) v = fmaxf(v, __shfl_xor(v, o, 64));
  return v;
}
__device__ __forceinline__ double wred_sumd(double v) {
#pragma unroll
  for (int o = 32; o > 0; o >>= 1) v += __shfl_xor(v, o, 64);
  return v;
}

#define GLD16(src, dst)                                                        \
  __builtin_amdgcn_global_load_lds(                                            \
      (const __attribute__((address_space(1))) void*)(src),                    \
      (__attribute__((address_space(3))) void*)(dst), 16, 0, 0)
#define GLD4(src, dst)                                                         \
  __builtin_amdgcn_global_load_lds(                                            \
      (const __attribute__((address_space(1))) void*)(src),                    \
      (__attribute__((address_space(3))) void*)(dst), 4, 0, 0)

// ---------------- fused prep: pgT (+stat cols), Av/Bv, G2, C3, zero f/cnt/n_km
__global__ void prep_all(const float* __restrict__ pr, const float* __restrict__ fg,
                         const float* __restrict__ fb, float* __restrict__ pgT,
                         float* __restrict__ Av, float* __restrict__ Bv,
                         float* __restrict__ G2, float* __restrict__ C3,
                         float* __restrict__ f, int* __restrict__ cnt,
                         int* __restrict__ n_km) {
  const int j = blockIdx.x, lane = threadIdx.x;
  if (j == 192) {
    float cg = 0.f, cgb = 0.f, cb = 0.f;
    for (int d = lane; d < D; d += 64) {
      const float g = fg[d], b = fb[d];
      G2[d] = g * g;
      cg = fmaf(g, g, cg);
      cgb = fmaf(g, b, cgb);
      cb = fmaf(b, b, cb);
    }
    cg = wred_sum(cg);
    cgb = wred_sum(cgb);
    cb = wred_sum(cb);
#pragma unroll
    for (int i = 0; i < 3; ++i) n_km[lane + 64 * i] = 0;
    if (lane == 0) { C3[0] = cg; C3[1] = cgb; C3[2] = cb; cnt[0] = 0; }
    return;
  }
  if (j < KM) {
    for (int d = lane; d < D; d += 64) f[(size_t)j * D + d] = 0.f;
  }
  if (j >= KM) {
    // stat columns: col 190 -> g^2 (gives Sum x g^2), col 191 -> g*b (Sum x g b)
    for (int d = lane; d < D; d += 64) {
      const float g = fg[d], b = fb[d];
      pgT[(size_t)d * KMP + j] = (j == KM) ? g * g : g * b;
    }
    if (lane == 0) { Av[j] = 0.f; Bv[j] = 0.f; }
    return;
  }
  float pv[12];
  float sp = 0.f;
#pragma unroll
  for (int jj = 0; jj < 12; ++jj) {
    const int d2 = lane + 64 * jj;
    pv[jj] = (d2 < D) ? pr[(size_t)j * D + d2] : 0.f;
    sp = fmaf(pv[jj], pv[jj], sp);
  }
  sp = wred_sum(sp);
  const float ip = 1.f / fmaxf(sqrtf(sp), 1e-12f);
  float sa = 0.f, sb = 0.f;
#pragma unroll
  for (int jj = 0; jj < 12; ++jj) {
    const int d2 = lane + 64 * jj;
    if (d2 < D) {
      const float ph = pv[jj] * ip;
      const float g = fg[d2], b = fb[d2];
      pgT[(size_t)d2 * KMP + j] = g * ph;
      sa = fmaf(g, ph, sa);
      sb = fmaf(b, ph, sb);
    }
  }
  sa = wred_sum(sa);
  sb = wred_sum(sb);
  if (lane == 0) { Av[j] = sa; Bv[j] = sb; }
}

// ---------------- main pass: DMA-staged GEMM on raw x + affine fixup + epilogue
__global__ __launch_bounds__(256, 3) void gemm_main(
    const float* __restrict__ x, const float* __restrict__ pgT,
    const float* __restrict__ Av, const float* __restrict__ Bv,
    const float* __restrict__ G2, const float* __restrict__ C3,
    const int* __restrict__ gt, float* __restrict__ out_seg,
    float* __restrict__ contrast, float* __restrict__ se,
    int* __restrict__ flags, const float* __restrict__ mn_g,
    const float* __restrict__ mn_b, const float* __restrict__ pn_g,
    const float* __restrict__ pn_b) {
  __shared__ union {
    struct {
      float PT[KC][KMP];   // 27648 B, contiguous for DMA
      float XL[TP][LDX];   // 22528 B row-major, ldx=44 (slot 9/10 pad)
      float G2c[64];       // 256 B (36 used)
    } st;
    float SIM[64][KMP];    // 49152 B (reused per half)
  } S;
  __shared__ float MU[TP], RS[TP], IL[TP];
  __shared__ float S1v[TP], S3v[TP];

  const int t = threadIdx.x;
  const int n0 = blockIdx.x * TP;
  const int pxg = t & 15;        // pixel group: px = pxg + 16*i, i=0..7
  const int prg = t >> 4;        // proto group: j = 12*prg + jj
  const int lane = t & 63, w = t >> 6;
  const int spx = 32 * w + (lane >> 1);  // stats pixel for this lane-pair
  const int sh = lane & 1;               // k-half (cols 0..17 / 18..35)

  const float Cgg = C3[0], Cgb = C3[1], Cbb = C3[2];

  float acc[8][12];
#pragma unroll
  for (int i = 0; i < 8; ++i)
#pragma unroll
    for (int jj = 0; jj < 12; ++jj) acc[i][jj] = 0.f;
  float s0 = 0.f, qs = 0.f, s2 = 0.f;

#pragma unroll 1
  for (int c = 0; c < NCH; ++c) {
    const int k0 = c * KC;
    __syncthreads();
    // --- async DMA staging (wave-uniform LDS base + lane*16 scatter) ---
    {
      const float* psrc = pgT + (size_t)k0 * KMP + (lane << 2);
      char* pdst = (char*)&S.st.PT[0][0];
      for (int i = w; i < 27; i += 4) GLD16(psrc + (i << 8), pdst + (i << 10));
      char* xdst = (char*)&S.st.XL[0][0];
      for (int i = w; i < 22; i += 4) {
        const int s = (i << 6) + lane;      // flat float4 slot, row-major ldx
        const int row = s / 11;
        int cc = s - row * 11;
        cc = cc > 8 ? 8 : cc;               // clamp pad slots (never read)
        GLD16(x + (size_t)(n0 + row) * D + k0 + (cc << 2), xdst + (i << 10));
      }
      if (w == 0) {
        const int gl = lane > 35 ? 35 : lane;
        GLD4(G2 + k0 + gl, (char*)&S.st.G2c[0]);
      }
    }
    __syncthreads();
    // --- register-tile FMA: 8 px x 12 protos, k vectorized by 4 ---
    const float4* XL4 = (const float4*)&S.st.XL[0][0];
    const float4* PT4 = (const float4*)&S.st.PT[0][0];
#pragma unroll 3
    for (int kc = 0; kc < 9; ++kc) {
      float4 xv[8];
#pragma unroll
      for (int i = 0; i < 8; ++i) xv[i] = XL4[(pxg + (i << 4)) * XSLOT + kc];
#pragma unroll
      for (int r = 0; r < 4; ++r) {
        const int kk = (kc << 2) + r;
        const float4 p0 = PT4[kk * 48 + 3 * prg + 0];
        const float4 p1 = PT4[kk * 48 + 3 * prg + 1];
        const float4 p2 = PT4[kk * 48 + 3 * prg + 2];
        const float pj[12] = {p0.x, p0.y, p0.z, p0.w, p1.x, p1.y,
                              p1.z, p1.w, p2.x, p2.y, p2.z, p2.w};
#pragma unroll
        for (int i = 0; i < 8; ++i) {
          const float xr = r == 0 ? xv[i].x : r == 1 ? xv[i].y
                         : r == 2 ? xv[i].z : xv[i].w;
#pragma unroll
          for (int jj = 0; jj < 12; ++jj)
            acc[i][jj] = fmaf(xr, pj[jj], acc[i][jj]);
        }
      }
    }
    // --- per-pixel stats (lane-pair splits k-halves): s0, q, Sum x^2 g^2 ---
    {
      const float2* xr2 = (const float2*)&S.st.XL[spx][18 * sh];
      const float2* gr2 = (const float2*)&S.st.G2c[18 * sh];
#pragma unroll
      for (int mm = 0; mm < 9; ++mm) {
        const float2 xv2 = xr2[mm];
        const float2 gv2 = gr2[mm];
        s0 += xv2.x + xv2.y;
        qs = fmaf(xv2.x, xv2.x, qs);
        qs = fmaf(xv2.y, xv2.y, qs);
        s2 = fmaf(xv2.x * xv2.x, gv2.x, s2);
        s2 = fmaf(xv2.y * xv2.y, gv2.y, s2);
      }
    }
  }

  // linear stats came out of the GEMM (cols 190, 191)
  if (prg == 15) {
#pragma unroll
    for (int i = 0; i < 8; ++i) {
      S1v[pxg + (i << 4)] = acc[i][10];
      S3v[pxg + (i << 4)] = acc[i][11];
    }
  }
  __syncthreads();
  s0 += __shfl_xor(s0, 1);
  qs += __shfl_xor(qs, 1);
  s2 += __shfl_xor(s2, 1);
  if (sh == 0) {
    const float muv = s0 / 720.f;
    const float var = qs / 720.f - muv * muv;
    const float rsv = 1.f / sqrtf(var + 1e-5f);
    const float s1v = S1v[spx], s3v = S3v[spx];
    const float L2v = rsv * rsv * (s2 - 2.f * muv * s1v + muv * muv * Cgg) +
                      2.f * rsv * (s3v - muv * Cgb) + Cbb;
    MU[spx] = muv;
    RS[spx] = rsv;
    IL[spx] = 1.f / fmaxf(sqrtf(fmaxf(L2v, 0.f)), 1e-12f);
  }

  float Aj[12], Bj[12];
#pragma unroll
  for (int jj = 0; jj < 12; ++jj) {
    Aj[jj] = Av[12 * prg + jj];
    Bj[jj] = Bv[12 * prg + jj];
  }
  const int j0 = lane, j1 = lane + 64, j2 = lane + 128;
  const bool ok2 = j2 < KM;
  const float pg0 = pn_g[j0], pb0 = pn_b[j0];
  const float pg1 = pn_g[j1], pb1 = pn_b[j1];
  const float pg2 = ok2 ? pn_g[j2] : 0.f, pb2 = ok2 ? pn_b[j2] : 0.f;
  const float mgv = lane < NCLS ? mn_g[lane] : 0.f;
  const float mbv = lane < NCLS ? mn_b[lane] : 0.f;

#pragma unroll
  for (int h = 0; h < 2; ++h) {
    __syncthreads();
    // fixup to cosine sims + SIM write for this half's 64 pixels
#pragma unroll
    for (int i2 = 0; i2 < 4; ++i2) {
      const int i = 4 * h + i2;
      const int px = pxg + (i << 4);
      const float muv = MU[px], rsv = RS[px], ilv = IL[px];
      float v[12];
#pragma unroll
      for (int jj = 0; jj < 12; ++jj)
        v[jj] = (rsv * (acc[i][jj] - muv * Aj[jj]) + Bj[jj]) * ilv;
      float4* dst = (float4*)&S.SIM[px - 64 * h][12 * prg];
      dst[0] = make_float4(v[0], v[1], v[2], v[3]);
      dst[1] = make_float4(v[4], v[5], v[6], v[7]);
      dst[2] = make_float4(v[8], v[9], v[10], v[11]);
    }
    __syncthreads();
    // epilogue: wave w handles local rows 16w..16w+15
    for (int pi = 0; pi < 16; ++pi) {
      const int pix = 16 * w + pi;
      const int n = n0 + 64 * h + pix;
      const float sv0 = S.SIM[pix][j0];
      const float sv1 = S.SIM[pix][j1];
      const float sv2 = ok2 ? S.SIM[pix][j2] : 0.f;
      float sum = wred_sum(sv0 + sv1 + sv2);
      const float mu = sum / 190.f;
      const float d0 = sv0 - mu, d1 = sv1 - mu, d2v = ok2 ? (sv2 - mu) : 0.f;
      float vs = wred_sum(d0 * d0 + d1 * d1 + d2v * d2v);
      const float rstd = 1.f / sqrtf(vs / 190.f + 1e-5f);
      contrast[(size_t)n * KM + j0] = d0 * rstd * pg0 + pb0;
      contrast[(size_t)n * KM + j1] = d1 * rstd * pg1 + pb1;
      if (ok2) contrast[(size_t)n * KM + j2] = d2v * rstd * pg2 + pb2;
      const int g0 = gt[n];
      const int b10 = g0 * 10;
      if (j0 >= b10 && j0 < b10 + 10) se[(size_t)n * 10 + (j0 - b10)] = sv0;
      if (j1 >= b10 && j1 < b10 + 10) se[(size_t)n * 10 + (j1 - b10)] = sv1;
      if (ok2 && j2 >= b10 && j2 < b10 + 10) se[(size_t)n * 10 + (j2 - b10)] = sv2;
      float mx = -3.0e38f;
      if (lane < NCLS) {
        const float* row = &S.SIM[pix][lane * 10];
#pragma unroll
        for (int m2 = 0; m2 < 10; ++m2) mx = fmaxf(mx, row[m2]);
      }
      float s19 = wred_sum(lane < NCLS ? mx : 0.f);
      const float mu19 = s19 / 19.f;
      const float dv = (lane < NCLS) ? (mx - mu19) : 0.f;
      float v19 = wred_sum(dv * dv);
      const float rs19 = 1.f / sqrtf(v19 / 19.f + 1e-5f);
      float key = -3.0e38f;
      if (lane < NCLS) {
        const float os = dv * rs19 * mgv + mbv;
        out_seg[(size_t)n * NCLS + lane] = os;
        key = os;
      }
      const float kmax = wred_max(key);
      const unsigned long long bm = __ballot(key == kmax);
      const int pred = __ffsll((unsigned long long)bm) - 1;
      if (lane == 0) flags[n] = (pred == g0) ? 1 : 0;
    }
  }
}

// ---------------- Sinkhorn column-sum pass; iter 0 caches e=exp(se/eps) in place
__global__ void sk_colsum(float* __restrict__ se, const int* __restrict__ gt,
                          const float* __restrict__ u, float* __restrict__ partials,
                          int iter, int nblk, int N) {
  __shared__ float Sl[KMP];
  const int t = threadIdx.x;
  if (t < KMP) Sl[t] = 0.f;
  __syncthreads();
  const int n = blockIdx.x * 256 + t;
  if (n < N) {
    const int b10 = gt[n] * 10;
    float e[10];
    if (iter == 0) {
#pragma unroll
      for (int m = 0; m < 10; ++m) {
        e[m] = expf(se[(size_t)n * 10 + m] / 0.05f);
        se[(size_t)n * 10 + m] = e[m];
      }
    } else {
#pragma unroll
      for (int m = 0; m < 10; ++m) e[m] = se[(size_t)n * 10 + m];
    }
    float a = 1.f;
    if (iter > 0) {
      float s = 0.f;
#pragma unroll
      for (int m = 0; m < 10; ++m) s = fmaf(e[m], u[b10 + m], s);
      a = (s > 0.f) ? 1.f / s : 0.f;
    }
#pragma unroll
    for (int m = 0; m < 10; ++m) atomicAdd(&Sl[b10 + m], a * e[m]);
  }
  __syncthreads();
  if (t < KM) partials[(size_t)t * nblk + blockIdx.x] = Sl[t];
}

__global__ void sk_reduce(const float* __restrict__ partials, float* __restrict__ u,
                          int nblk) {
  const int j = blockIdx.x, lane = threadIdx.x;
  double s = 0.0;
  for (int b = lane; b < nblk; b += 64) s += (double)partials[(size_t)j * nblk + b];
  s = wred_sumd(s);
  if (lane == 0) u[j] = (s > 0.0) ? (float)(1.0 / (10.0 * s)) : 0.f;
}

__global__ void sk_final(const float* __restrict__ se, const int* __restrict__ gt,
                         const float* __restrict__ u, const int* __restrict__ flags,
                         float* __restrict__ ptgt, int* __restrict__ list,
                         int* __restrict__ cnt, int* __restrict__ n_km, int N) {
  const int n = blockIdx.x * 256 + threadIdx.x;
  if (n >= N) return;
  const int g0 = gt[n], b10 = g0 * 10;
  float best = -1.f;
  int bi = 0;
#pragma unroll
  for (int m = 0; m < 10; ++m) {
    const float v = se[(size_t)n * 10 + m] * u[b10 + m];
    if (v > best) { best = v; bi = m; }
  }
  ptgt[n] = (float)(bi + 10 * g0);
  if (flags[n]) {
    atomicAdd(&n_km[b10 + bi], 1);
    const int p = atomicAdd(cnt, 1);
    list[p] = n | (bi << 20) | (g0 << 24);
  }
}

// ---------------- f accumulation over correct pixels (wave per pixel)
__global__ void f_accum(const float* __restrict__ x, const float* __restrict__ fg,
                        const float* __restrict__ fb, const int* __restrict__ list,
                        const int* __restrict__ cnt, float* __restrict__ f) {
  const int lane = threadIdx.x & 63;
  const int wid = (blockIdx.x * blockDim.x + threadIdx.x) >> 6;
  const int nw = (gridDim.x * blockDim.x) >> 6;
  const int total = *cnt;
  for (int i = wid; i < total; i += nw) {
    const int packed = list[i];
    const int n = packed & 0xFFFFF;
    const int m = (packed >> 20) & 0xF;
    const int k = (packed >> 24) & 0x1F;
    float xv[12];
    float s0 = 0.f, q = 0.f;
#pragma unroll
    for (int jj = 0; jj < 12; ++jj) {
      const int d2 = lane + 64 * jj;
      xv[jj] = (d2 < D) ? x[(size_t)n * D + d2] : 0.f;
      s0 += xv[jj];
      q = fmaf(xv[jj], xv[jj], q);
    }
    s0 = wred_sum(s0);
    q = wred_sum(q);
    const float mu = s0 / 720.f;
    const float var = q / 720.f - mu * mu;
    const float rs = 1.f / sqrtf(var + 1e-5f);
    float cv[12];
    float l2 = 0.f;
#pragma unroll
    for (int jj = 0; jj < 12; ++jj) {
      const int d2 = lane + 64 * jj;
      if (d2 < D) {
        cv[jj] = (xv[jj] - mu) * rs * fg[d2] + fb[d2];
        l2 = fmaf(cv[jj], cv[jj], l2);
      } else {
        cv[jj] = 0.f;
      }
    }
    l2 = wred_sum(l2);
    const float il = 1.f / fmaxf(sqrtf(l2), 1e-12f);
    float* frow = &f[(size_t)(k * 10 + m) * D];
#pragma unroll
    for (int jj = 0; jj < 12; ++jj) {
      const int d2 = lane + 64 * jj;
      if (d2 < D) atomicAdd(&frow[d2], cv[jj] * il);
    }
  }
}

// ---------------- prototype update (one wave per proto row)
__global__ void protos_out(const float* __restrict__ pr, const float* __restrict__ f,
                           const int* __restrict__ n_km, float* __restrict__ out) {
  const int j = blockIdx.x, lane = threadIdx.x;
  float pv[12], fv[12];
  float sp = 0.f, sf = 0.f;
#pragma unroll
  for (int jj = 0; jj < 12; ++jj) {
    const int d2 = lane + 64 * jj;
    pv[jj] = (d2 < D) ? pr[(size_t)j * D + d2] : 0.f;
    fv[jj] = (d2 < D) ? f[(size_t)j * D + d2] : 0.f;
    sp = fmaf(pv[jj], pv[jj], sp);
    sf = fmaf(fv[jj], fv[jj], sf);
  }
  sp = wred_sum(sp);
  sf = wred_sum(sf);
  const float ip = 1.f / fmaxf(sqrtf(sp), 1e-12f);
  const float iff = 1.f / fmaxf(sqrtf(sf), 1e-12f);
  const bool valid = n_km[j] > 0;
  float vv[12];
  float sv = 0.f;
#pragma unroll
  for (int jj = 0; jj < 12; ++jj) {
    const float ph = pv[jj] * ip;
    vv[jj] = valid ? (0.999f * ph + 0.001f * (fv[jj] * iff)) : ph;
    sv = fmaf(vv[jj], vv[jj], sv);
  }
  sv = wred_sum(sv);
  const float ivv = 1.f / fmaxf(sqrtf(sv), 1e-12f);
#pragma unroll
  for (int jj = 0; jj < 12; ++jj) {
    const int d2 = lane + 64 * jj;
    if (d2 < D) out[(size_t)j * D + d2] = vv[jj] * ivv;
  }
}

extern "C" void kernel_launch(void* const* d_in, const int* in_sizes, int n_in,
                              void* d_out, int out_size, void* d_ws, size_t ws_size,
                              hipStream_t stream) {
  const float* x = (const float*)d_in[0];
  const float* protos = (const float*)d_in[1];
  const float* fn_g = (const float*)d_in[2];
  const float* fn_b = (const float*)d_in[3];
  const float* mn_g = (const float*)d_in[4];
  const float* mn_b = (const float*)d_in[5];
  const float* pn_g = (const float*)d_in[6];
  const float* pn_b = (const float*)d_in[7];
  const int* gt = (const int*)d_in[8];
  const int N = in_sizes[0] / D;

  float* out_seg = (float*)d_out;
  float* contrast = out_seg + (size_t)N * NCLS;
  float* ptgt = contrast + (size_t)N * KM;
  float* pnew = ptgt + (size_t)N;

  char* ws = (char*)d_ws;
  size_t off = 0;
  auto alloc = [&](size_t bytes) {
    char* p = ws + off;
    off = (off + bytes + 255) & ~(size_t)255;
    return p;
  };
  const int nblk = (N + 255) / 256;
  float* pgT = (float*)alloc((size_t)D * KMP * 4 + 1024);
  float* Av = (float*)alloc(KMP * 4);
  float* Bv = (float*)alloc(KMP * 4);
  float* G2 = (float*)alloc(D * 4);
  float* C3 = (float*)alloc(4 * 4);
  float* se = (float*)alloc((size_t)N * 10 * 4);
  float* partials = (float*)alloc((size_t)KM * nblk * 4);
  float* u = (float*)alloc(KMP * 4);
  float* f = (float*)alloc((size_t)KM * D * 4);
  int* n_km = (int*)alloc(KMP * 4);
  int* flags = (int*)alloc((size_t)N * 4);
  int* list = (int*)alloc((size_t)N * 4);
  int* cnt = (int*)alloc(256);

  prep_all<<<193, 64, 0, stream>>>(protos, fn_g, fn_b, pgT, Av, Bv, G2, C3, f,
                                   cnt, n_km);
  gemm_main<<<N / TP, 256, 0, stream>>>(x, pgT, Av, Bv, G2, C3, gt, out_seg,
                                        contrast, se, flags, mn_g, mn_b, pn_g,
                                        pn_b);
  for (int it = 0; it < 3; ++it) {
    sk_colsum<<<nblk, 256, 0, stream>>>(se, gt, u, partials, it, nblk, N);
    sk_reduce<<<KM, 64, 0, stream>>>(partials, u, nblk);
  }
  sk_final<<<nblk, 256, 0, stream>>>(se, gt, u, flags, ptgt, list, cnt, n_km, N);
  f_accum<<<256, 256, 0, stream>>>(x, fn_g, fn_b, list, cnt, f);
  protos_out<<<KM, 64, 0, stream>>>(protos, f, n_km, pnew);
}